// Round 1
// 323.389 us; speedup vs baseline: 5.6555x; 5.6555x over previous
//
#include <hip/hip_runtime.h>
#include <cstddef>
#include <cstdint>

#define NN 8192
#define DD 128
#define KP 256          // concat K per split part: [YS|Y] / [X|XS]
#define BM 128
#define BN 128
#define BK 32
#define JSPLIT 8
#define JRANGE (NN / JSPLIT)    // 1024
#define NJT (JRANGE / BN)       // 8

typedef __attribute__((ext_vector_type(8))) short bf16x8;
typedef __attribute__((ext_vector_type(4))) float f32x4;
typedef unsigned short u16;
typedef unsigned int   u32;

__device__ __forceinline__ u16 f2bf(float x) {
    u32 u = __float_as_uint(x);
    u32 r = (u + 0x7fffu + ((u >> 16) & 1u)) >> 16;   // round-to-nearest-even
    return (u16)r;
}
__device__ __forceinline__ float bf2f(u16 h) {
    return __uint_as_float(((u32)h) << 16);
}

// async global->LDS, 16B per lane; LDS dest must be wave-uniform base (+lane*16 by HW)
#define GLDS16(gp, lp) __builtin_amdgcn_global_load_lds( \
    (const __attribute__((address_space(1))) void*)(gp), \
    (__attribute__((address_space(3))) void*)(lp), 16, 0, 0)

// ---------------------------------------------------------------------------
// k1: XS=X@S, YS=Y@S, qX, qY; emit bf16 hi/lo panels Ah/Al=[YS|Y], Bh/Bl=[X|XS]
// (row-major [8192][256]), XST = bf16 XS^T [128][8192], YSrm fp32 [8192][128].
// ---------------------------------------------------------------------------
__global__ __launch_bounds__(256) void k1_precompute(
    const float* __restrict__ X, const float* __restrict__ Y,
    const float* __restrict__ S,
    u16* __restrict__ Ah, u16* __restrict__ Al,
    u16* __restrict__ Bh, u16* __restrict__ Bl,
    u16* __restrict__ XST, float* __restrict__ YSrm,
    float* __restrict__ qX, float* __restrict__ qY)
{
    __shared__ float Xs[16][128];
    __shared__ float Ys[16][128];
    __shared__ float XSb[16][129];
    __shared__ float YSb[16][129];
    const int t  = threadIdx.x;
    const int i0 = blockIdx.x * 16;

    #pragma unroll
    for (int p = 0; p < 2; ++p) {
        int f4 = t + p * 256;          // 0..511
        int r  = f4 >> 5;
        int c  = (f4 & 31) * 4;
        *reinterpret_cast<float4*>(&Xs[r][c]) =
            *reinterpret_cast<const float4*>(X + (size_t)(i0 + r) * DD + c);
        *reinterpret_cast<float4*>(&Ys[r][c]) =
            *reinterpret_cast<const float4*>(Y + (size_t)(i0 + r) * DD + c);
    }
    __syncthreads();

    const int d    = t & 127;
    const int half = t >> 7;
    float xsa[8], ysa[8];
    #pragma unroll
    for (int r = 0; r < 8; ++r) { xsa[r] = 0.f; ysa[r] = 0.f; }
    for (int k = 0; k < DD; ++k) {
        float sv = S[k * DD + d];
        #pragma unroll
        for (int r = 0; r < 8; ++r) {
            xsa[r] = fmaf(Xs[half*8 + r][k], sv, xsa[r]);
            ysa[r] = fmaf(Ys[half*8 + r][k], sv, ysa[r]);
        }
    }
    #pragma unroll
    for (int r = 0; r < 8; ++r) {
        XSb[half*8 + r][d] = xsa[r];
        YSb[half*8 + r][d] = ysa[r];
    }
    __syncthreads();

    if (t < 16) {
        float s = 0.f;
        for (int k = 0; k < DD; ++k) s += Xs[t][k] * XSb[t][k];
        qX[i0 + t] = s;
    } else if (t < 32) {
        int r = t - 16;
        float s = 0.f;
        for (int k = 0; k < DD; ++k) s += Ys[r][k] * YSb[r][k];
        qY[i0 + r] = s;
    }

    // hi/lo split panels, 2 cols per u32 store
    #pragma unroll
    for (int p = 0; p < 8; ++p) {
        int e  = t + p * 256;          // 0..2047
        int r  = e >> 7;               // 0..15
        int c2 = (e & 127) * 2;        // 0,2,..,254
        float a0 = (c2     < 128) ? YSb[r][c2]         : Ys[r][c2 - 128];
        float a1 = (c2 + 1 < 128) ? YSb[r][c2 + 1]     : Ys[r][c2 + 1 - 128];
        float b0 = (c2     < 128) ? Xs[r][c2]          : XSb[r][c2 - 128];
        float b1 = (c2 + 1 < 128) ? Xs[r][c2 + 1]      : XSb[r][c2 + 1 - 128];
        u16 ah0 = f2bf(a0), ah1 = f2bf(a1);
        u16 al0 = f2bf(a0 - bf2f(ah0)), al1 = f2bf(a1 - bf2f(ah1));
        u16 bh0 = f2bf(b0), bh1 = f2bf(b1);
        u16 bl0 = f2bf(b0 - bf2f(bh0)), bl1 = f2bf(b1 - bf2f(bh1));
        size_t off = (size_t)(i0 + r) * KP + c2;
        *reinterpret_cast<u32*>(Ah + off) = (u32)ah0 | ((u32)ah1 << 16);
        *reinterpret_cast<u32*>(Al + off) = (u32)al0 | ((u32)al1 << 16);
        *reinterpret_cast<u32*>(Bh + off) = (u32)bh0 | ((u32)bh1 << 16);
        *reinterpret_cast<u32*>(Bl + off) = (u32)bl0 | ((u32)bl1 << 16);
    }
    // XS^T bf16
    #pragma unroll
    for (int p = 0; p < 8; ++p) {
        int e  = t + p * 256;          // 0..2047
        int dd = e >> 4;               // 0..127
        int r  = e & 15;
        XST[(size_t)dd * NN + i0 + r] = f2bf(XSb[r][dd]);
    }
    // YS fp32 row-major
    #pragma unroll
    for (int p = 0; p < 8; ++p) {
        int e  = t + p * 256;
        int r  = e >> 7;
        int dd = e & 127;
        YSrm[(size_t)(i0 + r) * DD + dd] = YSb[r][dd];
    }
}

// ---------------------------------------------------------------------------
// k2: per 128x128 tile: cross = Ah.Bh^T + Ah.Bl^T + Al.Bh^T via MFMA (K=768),
// K = exp(-0.5*(qY+qX-cross)) -> Kout + bf16 into swizzled LDS, then
// phase 2 MFMA: dacc[i][d] += K[i][j] * XS[j][d]. rowsum via shfl butterfly.
// LDS: [0,16K) As|Bs phase-1 staging, [0,32K) A2 (aliases, epilogue/phase2),
//      [32K,64K) XT2 (XS^T tile). 64KB total -> 2 blocks/CU.
// ---------------------------------------------------------------------------
__global__ __launch_bounds__(256, 2) void k2_main(
    const u16* __restrict__ Ah, const u16* __restrict__ Al,
    const u16* __restrict__ Bh, const u16* __restrict__ Bl,
    const u16* __restrict__ XST,
    const float* __restrict__ qX, const float* __restrict__ qY,
    float* __restrict__ Kout, float* __restrict__ dKacc,
    float* __restrict__ rowsum)
{
    __shared__ unsigned char smem[65536];
    u16* const As = (u16*)smem;             // [128][32] bf16, linear (m97 layout)
    u16* const Bs = (u16*)(smem + 8192);    // [128][32] bf16

    const int t    = threadIdx.x;
    const int wid  = t >> 6;
    const int lane = t & 63;
    const int lq   = lane >> 4;             // quarter 0..3
    const int lc   = lane & 15;
    const int wr   = wid >> 1;              // i 64-half
    const int wc   = wid & 1;               // j/d 64-half

    const int strip = blockIdx.x & 63;
    const int jsp   = blockIdx.x >> 6;
    const int ib    = strip * BM;
    const int jbase = jsp * JRANGE;

    // per-block row constants (16 rows owned per lane across frags)
    float qYr[16];
    #pragma unroll
    for (int mi = 0; mi < 4; ++mi)
        #pragma unroll
        for (int r = 0; r < 4; ++r)
            qYr[mi*4 + r] = qY[ib + wr*64 + mi*16 + lq*4 + r];

    f32x4 dacc[4][4];
    #pragma unroll
    for (int a = 0; a < 4; ++a)
        #pragma unroll
        for (int b = 0; b < 4; ++b)
            dacc[a][b] = (f32x4){0.f, 0.f, 0.f, 0.f};
    float rs[16];
    #pragma unroll
    for (int q = 0; q < 16; ++q) rs[q] = 0.f;

    for (int jt = 0; jt < NJT; ++jt) {
        const int jb = jbase + jt * BN;

        __syncthreads();   // prev phase-2 reads of A2/XT2 done before restage

        // stage XS^T tile (d-major [128][128] bf16), source chunk pre-swizzled
        // so a swizzled read (granule ^= d&7) returns linear data (rule #21)
        #pragma unroll
        for (int c = 0; c < 8; ++c) {
            int dd = (wid*8 + c)*4 + lq;          // 0..127
            int ch = lc ^ (dd & 7);               // 16B-granule in row
            GLDS16(XST + (size_t)dd * NN + jb + ch*8,
                   smem + 32768 + (size_t)(wid*8 + c) * 1024);
        }

        f32x4 acc[4][4];
        #pragma unroll
        for (int a = 0; a < 4; ++a)
            #pragma unroll
            for (int b = 0; b < 4; ++b)
                acc[a][b] = (f32x4){0.f, 0.f, 0.f, 0.f};

        // split-bf16 passes: Ah*Bh + Ah*Bl + Al*Bh
        for (int pass = 0; pass < 3; ++pass) {
            const u16* Ap = (pass == 2) ? Al : Ah;
            const u16* Bp = (pass == 1) ? Bl : Bh;
            for (int kt = 0; kt < KP / BK; ++kt) {
                const int kc = kt * BK;
                __syncthreads();               // prior frag reads done
                #pragma unroll
                for (int c = 0; c < 2; ++c) {
                    const int rr = (c*4 + wid)*16 + (lane >> 2);
                    const int ch = (lane & 3) * 8;
                    GLDS16(Ap + (size_t)(ib + rr) * KP + kc + ch,
                           smem + (size_t)(c*4 + wid) * 1024);
                    GLDS16(Bp + (size_t)(jb + rr) * KP + kc + ch,
                           smem + 8192 + (size_t)(c*4 + wid) * 1024);
                }
                __syncthreads();               // drains vmcnt before barrier
                bf16x8 af[4], bfr[4];
                #pragma unroll
                for (int mi = 0; mi < 4; ++mi)
                    af[mi] = *reinterpret_cast<const bf16x8*>(
                        As + (wr*64 + mi*16 + lc) * BK + lq*8);
                #pragma unroll
                for (int ni = 0; ni < 4; ++ni)
                    bfr[ni] = *reinterpret_cast<const bf16x8*>(
                        Bs + (wc*64 + ni*16 + lc) * BK + lq*8);
                #pragma unroll
                for (int mi = 0; mi < 4; ++mi)
                    #pragma unroll
                    for (int ni = 0; ni < 4; ++ni)
                        acc[mi][ni] = __builtin_amdgcn_mfma_f32_16x16x32_bf16(
                            af[mi], bfr[ni], acc[mi][ni], 0, 0, 0);
            }
        }
        __syncthreads();   // all frag reads done before A2 overwrites As/Bs

        // epilogue: quad -> K; store fp32 K; bf16 K into swizzled A2
        float qXv[4];
        #pragma unroll
        for (int ni = 0; ni < 4; ++ni)
            qXv[ni] = qX[jb + wc*64 + ni*16 + lc];

        #pragma unroll
        for (int mi = 0; mi < 4; ++mi) {
            const int row = ib + wr*64 + mi*16 + lq*4;
            #pragma unroll
            for (int ni = 0; ni < 4; ++ni) {
                const int col = jb + wc*64 + ni*16 + lc;
                float kq[4];
                #pragma unroll
                for (int r = 0; r < 4; ++r) {
                    float quad = qYr[mi*4 + r] + qXv[ni] - acc[mi][ni][r];
                    kq[r] = __expf(-0.5f * quad);
                    rs[mi*4 + r] += kq[r];
                }
                #pragma unroll
                for (int r = 0; r < 4; ++r)
                    Kout[(size_t)(row + r) * NN + col] = kq[r];
                #pragma unroll
                for (int r = 0; r < 4; ++r) {
                    const int rl = wr*64 + mi*16 + lq*4 + r;
                    const int cl = wc*64 + ni*16 + lc;
                    const int by = rl*256 + ((cl*2) ^ ((rl & 7) << 4));
                    *reinterpret_cast<u16*>(smem + by) = f2bf(kq[r]);
                }
            }
        }
        __syncthreads();   // A2 written by all; XT2 loads drained

        // phase 2: dacc[i][d] += K_tile[i][j] * XS[j][d], K-dim = j (4 steps)
        #pragma unroll
        for (int kb = 0; kb < 4; ++kb) {
            bf16x8 pa[4], pb[4];
            #pragma unroll
            for (int mi = 0; mi < 4; ++mi) {
                const int rl = wr*64 + mi*16 + lc;
                const int gr = (kb*4 + lq) ^ (rl & 7);
                pa[mi] = *reinterpret_cast<const bf16x8*>(smem + rl*256 + gr*16);
            }
            #pragma unroll
            for (int di = 0; di < 4; ++di) {
                const int dl = wc*64 + di*16 + lc;
                const int gr = (kb*4 + lq) ^ (dl & 7);
                pb[di] = *reinterpret_cast<const bf16x8*>(smem + 32768 + dl*256 + gr*16);
            }
            #pragma unroll
            for (int mi = 0; mi < 4; ++mi)
                #pragma unroll
                for (int di = 0; di < 4; ++di)
                    dacc[mi][di] = __builtin_amdgcn_mfma_f32_16x16x32_bf16(
                        pa[mi], pb[di], dacc[mi][di], 0, 0, 0);
        }
    }

    // write out dacc (atomic: JSPLIT blocks per i-strip) and rowsum
    #pragma unroll
    for (int mi = 0; mi < 4; ++mi) {
        const int row = ib + wr*64 + mi*16 + lq*4;
        #pragma unroll
        for (int di = 0; di < 4; ++di) {
            const int col = wc*64 + di*16 + lc;
            #pragma unroll
            for (int r = 0; r < 4; ++r)
                atomicAdd(&dKacc[(size_t)(row + r) * DD + col], dacc[mi][di][r]);
        }
    }
    #pragma unroll
    for (int q = 0; q < 16; ++q) {
        float v = rs[q];
        v += __shfl_xor(v, 1);
        v += __shfl_xor(v, 2);
        v += __shfl_xor(v, 4);
        v += __shfl_xor(v, 8);
        if (lc == 0) {
            const int mi = q >> 2, r = q & 3;
            atomicAdd(&rowsum[ib + wr*64 + mi*16 + lq*4 + r], v);
        }
    }
}

// dK = 2*(rowsum[i]*YS[i][d] - acc[i][d]); acc lives in dK buffer (in-place)
__global__ __launch_bounds__(256) void k3_finalize(
    const float* __restrict__ rowsum, const float* __restrict__ YSrm,
    float* __restrict__ dK)
{
    int idx = blockIdx.x * 256 + threadIdx.x;
    int i = idx >> 7;
    dK[idx] = 2.0f * (rowsum[i] * YSrm[idx] - dK[idx]);
}

extern "C" void kernel_launch(void* const* d_in, const int* in_sizes, int n_in,
                              void* d_out, int out_size, void* d_ws, size_t ws_size,
                              hipStream_t stream)
{
    const float* X = (const float*)d_in[0];
    const float* Y = (const float*)d_in[1];
    const float* S = (const float*)d_in[2];
    float* Kout = (float*)d_out;
    float* dK   = Kout + (size_t)NN * NN;

    // ws layout (22.1 MB): Ah,Al,Bh,Bl 4x4MB bf16, XST 2MB, YSrm 4MB, qX/qY/rsum
    u16* Ah  = (u16*)d_ws;
    u16* Al  = Ah + (size_t)NN * KP;
    u16* Bh  = Al + (size_t)NN * KP;
    u16* Bl  = Bh + (size_t)NN * KP;
    u16* XST = Bl + (size_t)NN * KP;
    float* YSrm = (float*)(XST + (size_t)DD * NN);
    float* qX   = YSrm + (size_t)NN * DD;
    float* qY   = qX + NN;
    float* rsum = qY + NN;

    hipMemsetAsync(dK, 0, (size_t)NN * DD * sizeof(float), stream);
    hipMemsetAsync(rsum, 0, (size_t)NN * sizeof(float), stream);

    k1_precompute<<<NN / 16, 256, 0, stream>>>(X, Y, S, Ah, Al, Bh, Bl, XST, YSrm, qX, qY);
    k2_main<<<64 * JSPLIT, 256, 0, stream>>>(Ah, Al, Bh, Bl, XST, qX, qY, Kout, dK, rsum);
    k3_finalize<<<(NN * DD) / 256, 256, 0, stream>>>(rsum, YSrm, dK);
}

// Round 2
// 311.595 us; speedup vs baseline: 5.8695x; 1.0379x over previous
//
#include <hip/hip_runtime.h>
#include <cstddef>
#include <cstdint>

#define NN 8192
#define DD 128
#define KP 256          // concat K per split part: [YS|Y] / [X|XS]
#define BM 128
#define BN 128
#define BK 32
#define JSPLIT 8
#define JRANGE (NN / JSPLIT)    // 1024
#define NJT (JRANGE / BN)       // 8

typedef __attribute__((ext_vector_type(8))) short bf16x8;
typedef __attribute__((ext_vector_type(4))) float f32x4;
typedef unsigned short u16;
typedef unsigned int   u32;

__device__ __forceinline__ u16 f2bf(float x) {
    u32 u = __float_as_uint(x);
    u32 r = (u + 0x7fffu + ((u >> 16) & 1u)) >> 16;   // round-to-nearest-even
    return (u16)r;
}
__device__ __forceinline__ float bf2f(u16 h) {
    return __uint_as_float(((u32)h) << 16);
}

// async global->LDS, 16B per lane; LDS dest is wave-uniform base (+lane*16 by HW)
#define GLDS16(gp, lp) __builtin_amdgcn_global_load_lds( \
    (const __attribute__((address_space(1))) void*)(gp), \
    (__attribute__((address_space(3))) void*)(lp), 16, 0, 0)

#define VMCNT(n) asm volatile("s_waitcnt vmcnt(" #n ")" ::: "memory")
#define BARRIER() do { __builtin_amdgcn_s_barrier(); asm volatile("" ::: "memory"); } while (0)

// 16B-chunk swizzle within a 64B staging row: free 2-way bank pattern on read
#define SWZ_CHUNK(row, c) ((c) ^ (((row) >> 1) & 3))

// ---------------------------------------------------------------------------
// k1: XS=X@S, YS=Y@S, qX, qY; emit bf16 hi/lo panels Ah/Al=[YS|Y], Bh/Bl=[X|XS]
// (row-major [8192][256]), XST = bf16 XS^T [128][8192], YSrm fp32 [8192][128].
// ---------------------------------------------------------------------------
__global__ __launch_bounds__(256) void k1_precompute(
    const float* __restrict__ X, const float* __restrict__ Y,
    const float* __restrict__ S,
    u16* __restrict__ Ah, u16* __restrict__ Al,
    u16* __restrict__ Bh, u16* __restrict__ Bl,
    u16* __restrict__ XST, float* __restrict__ YSrm,
    float* __restrict__ qX, float* __restrict__ qY)
{
    __shared__ float Xs[16][128];
    __shared__ float Ys[16][128];
    __shared__ float XSb[16][129];
    __shared__ float YSb[16][129];
    const int t  = threadIdx.x;
    const int i0 = blockIdx.x * 16;

    #pragma unroll
    for (int p = 0; p < 2; ++p) {
        int f4 = t + p * 256;          // 0..511
        int r  = f4 >> 5;
        int c  = (f4 & 31) * 4;
        *reinterpret_cast<float4*>(&Xs[r][c]) =
            *reinterpret_cast<const float4*>(X + (size_t)(i0 + r) * DD + c);
        *reinterpret_cast<float4*>(&Ys[r][c]) =
            *reinterpret_cast<const float4*>(Y + (size_t)(i0 + r) * DD + c);
    }
    __syncthreads();

    const int d    = t & 127;
    const int half = t >> 7;
    float xsa[8], ysa[8];
    #pragma unroll
    for (int r = 0; r < 8; ++r) { xsa[r] = 0.f; ysa[r] = 0.f; }
    for (int k = 0; k < DD; ++k) {
        float sv = S[k * DD + d];
        #pragma unroll
        for (int r = 0; r < 8; ++r) {
            xsa[r] = fmaf(Xs[half*8 + r][k], sv, xsa[r]);
            ysa[r] = fmaf(Ys[half*8 + r][k], sv, ysa[r]);
        }
    }
    #pragma unroll
    for (int r = 0; r < 8; ++r) {
        XSb[half*8 + r][d] = xsa[r];
        YSb[half*8 + r][d] = ysa[r];
    }
    __syncthreads();

    if (t < 16) {
        float s = 0.f;
        for (int k = 0; k < DD; ++k) s += Xs[t][k] * XSb[t][k];
        qX[i0 + t] = s;
    } else if (t < 32) {
        int r = t - 16;
        float s = 0.f;
        for (int k = 0; k < DD; ++k) s += Ys[r][k] * YSb[r][k];
        qY[i0 + r] = s;
    }

    // hi/lo split panels, 2 cols per u32 store
    #pragma unroll
    for (int p = 0; p < 8; ++p) {
        int e  = t + p * 256;          // 0..2047
        int r  = e >> 7;               // 0..15
        int c2 = (e & 127) * 2;        // 0,2,..,254
        float a0 = (c2     < 128) ? YSb[r][c2]         : Ys[r][c2 - 128];
        float a1 = (c2 + 1 < 128) ? YSb[r][c2 + 1]     : Ys[r][c2 + 1 - 128];
        float b0 = (c2     < 128) ? Xs[r][c2]          : XSb[r][c2 - 128];
        float b1 = (c2 + 1 < 128) ? Xs[r][c2 + 1]      : XSb[r][c2 + 1 - 128];
        u16 ah0 = f2bf(a0), ah1 = f2bf(a1);
        u16 al0 = f2bf(a0 - bf2f(ah0)), al1 = f2bf(a1 - bf2f(ah1));
        u16 bh0 = f2bf(b0), bh1 = f2bf(b1);
        u16 bl0 = f2bf(b0 - bf2f(bh0)), bl1 = f2bf(b1 - bf2f(bh1));
        size_t off = (size_t)(i0 + r) * KP + c2;
        *reinterpret_cast<u32*>(Ah + off) = (u32)ah0 | ((u32)ah1 << 16);
        *reinterpret_cast<u32*>(Al + off) = (u32)al0 | ((u32)al1 << 16);
        *reinterpret_cast<u32*>(Bh + off) = (u32)bh0 | ((u32)bh1 << 16);
        *reinterpret_cast<u32*>(Bl + off) = (u32)bl0 | ((u32)bl1 << 16);
    }
    // XS^T bf16
    #pragma unroll
    for (int p = 0; p < 8; ++p) {
        int e  = t + p * 256;          // 0..2047
        int dd = e >> 4;               // 0..127
        int r  = e & 15;
        XST[(size_t)dd * NN + i0 + r] = f2bf(XSb[r][dd]);
    }
    // YS fp32 row-major
    #pragma unroll
    for (int p = 0; p < 8; ++p) {
        int e  = t + p * 256;
        int r  = e >> 7;
        int dd = e & 127;
        YSrm[(size_t)(i0 + r) * DD + dd] = YSb[r][dd];
    }
}

// ---------------------------------------------------------------------------
// k2: cross = Ah.Bh^T + Ah.Bl^T + Al.Bh^T via MFMA (K=768, 24 k-steps),
// triple-buffered global_load_lds staging with counted vmcnt + raw barriers,
// K = exp(-0.5*(qY+qX-cross)) -> Kout (NT stores) + bf16 into swizzled LDS,
// phase 2 MFMA: dacc[i][d] += K[i][j] * XS[j][d].
// LDS map: b0 [0,16K) b1 [16K,32K) b2 [32K,48K) XT2 [48K,80K); A2 aliases b0+b1.
// ---------------------------------------------------------------------------
__device__ __forceinline__ void get_ops(
    const u16* Ah, const u16* Al, const u16* Bh, const u16* Bl,
    int kg, const u16** Ap, const u16** Bp, int* kc)
{
    const int pass = kg >> 3;
    *kc = (kg & 7) * BK;
    *Ap = (pass == 2) ? Al : Ah;
    *Bp = (pass == 1) ? Bl : Bh;
}

__device__ __forceinline__ void stage_ab(
    const u16* __restrict__ Ap, const u16* __restrict__ Bp,
    int ib, int jb, int kc, unsigned char* lds, int wid, int lane)
{
    #pragma unroll
    for (int c = 0; c < 2; ++c) {
        const int chunk = c * 4 + wid;                 // wave-uniform 0..7
        const int rr = chunk * 16 + (lane >> 2);       // row 0..127
        const int cc = SWZ_CHUNK(rr, lane & 3) * 8;    // swizzled u16 col
        GLDS16(Ap + (size_t)(ib + rr) * KP + kc + cc, lds + chunk * 1024);
        GLDS16(Bp + (size_t)(jb + rr) * KP + kc + cc, lds + 8192 + chunk * 1024);
    }
}

__global__ __launch_bounds__(256, 2) void k2_main(
    const u16* __restrict__ Ah, const u16* __restrict__ Al,
    const u16* __restrict__ Bh, const u16* __restrict__ Bl,
    const u16* __restrict__ XST,
    const float* __restrict__ qX, const float* __restrict__ qY,
    float* __restrict__ Kout, float* __restrict__ dKacc,
    float* __restrict__ rowsum)
{
    __shared__ unsigned char smem[81920];

    const int t    = threadIdx.x;
    const int wid  = t >> 6;
    const int lane = t & 63;
    const int lq   = lane >> 4;             // quarter 0..3
    const int lc   = lane & 15;
    const int wr   = wid >> 1;              // i 64-half
    const int wc   = wid & 1;               // j/d 64-half

    // XCD-aware bijective swizzle (512 blocks, 8 XCDs): XCD x owns jsp x
    const int bid     = blockIdx.x;
    const int logical = ((bid & 7) << 6) | (bid >> 3);
    const int strip   = logical & 63;
    const int jsp     = logical >> 6;
    const int ib      = strip * BM;
    const int jbase   = jsp * JRANGE;

    float qYr[16];
    #pragma unroll
    for (int mi = 0; mi < 4; ++mi)
        #pragma unroll
        for (int r = 0; r < 4; ++r)
            qYr[mi*4 + r] = qY[ib + wr*64 + mi*16 + lq*4 + r];

    f32x4 dacc[4][4];
    #pragma unroll
    for (int a = 0; a < 4; ++a)
        #pragma unroll
        for (int b = 0; b < 4; ++b)
            dacc[a][b] = (f32x4){0.f, 0.f, 0.f, 0.f};
    float rs[16];
    #pragma unroll
    for (int q = 0; q < 16; ++q) rs[q] = 0.f;

    for (int jt = 0; jt < NJT; ++jt) {
        const int jb = jbase + jt * BN;

        // ---- prologue: stage kg=0 -> b0, kg=1 -> b1, then XT2 prefetch ----
        {
            const u16 *Ap, *Bp; int kc;
            get_ops(Ah, Al, Bh, Bl, 0, &Ap, &Bp, &kc);
            stage_ab(Ap, Bp, ib, jb, kc, smem, wid, lane);
            get_ops(Ah, Al, Bh, Bl, 1, &Ap, &Bp, &kc);
            stage_ab(Ap, Bp, ib, jb, kc, smem + 16384, wid, lane);
        }
        #pragma unroll
        for (int c = 0; c < 8; ++c) {
            int dd = (wid*8 + c)*4 + lq;          // 0..127
            int ch = lc ^ (dd & 7);               // pre-swizzled 16B granule
            GLDS16(XST + (size_t)dd * NN + jb + ch*8,
                   smem + 49152 + (size_t)(wid*8 + c) * 1024);
        }
        VMCNT(12);          // s0 complete (s1 + XT2 still in flight)
        BARRIER();

        f32x4 acc[4][4];
        #pragma unroll
        for (int a = 0; a < 4; ++a)
            #pragma unroll
            for (int b = 0; b < 4; ++b)
                acc[a][b] = (f32x4){0.f, 0.f, 0.f, 0.f};

        // ---- main pipeline: 24 regions, one barrier each, counted vmcnt ----
        #pragma unroll 3
        for (int kg = 0; kg < 24; ++kg) {
            if (kg <= 21) {
                const u16 *Ap, *Bp; int kc;
                get_ops(Ah, Al, Bh, Bl, kg + 2, &Ap, &Bp, &kc);
                stage_ab(Ap, Bp, ib, jb, kc, smem + ((kg + 2) % 3) * 16384, wid, lane);
            }
            const u16* AsB = (const u16*)(smem + (kg % 3) * 16384);
            const u16* BsB = AsB + 4096;           // +8192 bytes

            bf16x8 af[4], bfr[4];
            #pragma unroll
            for (int mi = 0; mi < 4; ++mi) {
                const int ar = wr*64 + mi*16 + lc;
                af[mi] = *reinterpret_cast<const bf16x8*>(
                    AsB + ar * BK + SWZ_CHUNK(ar, lq) * 8);
            }
            #pragma unroll
            for (int ni = 0; ni < 4; ++ni) {
                const int br = wc*64 + ni*16 + lc;
                bfr[ni] = *reinterpret_cast<const bf16x8*>(
                    BsB + br * BK + SWZ_CHUNK(br, lq) * 8);
            }
            __builtin_amdgcn_s_setprio(1);
            #pragma unroll
            for (int mi = 0; mi < 4; ++mi)
                #pragma unroll
                for (int ni = 0; ni < 4; ++ni)
                    acc[mi][ni] = __builtin_amdgcn_mfma_f32_16x16x32_bf16(
                        af[mi], bfr[ni], acc[mi][ni], 0, 0, 0);
            __builtin_amdgcn_s_setprio(0);

            if (kg == 0)       VMCNT(12);   // drain s1 (XT2+s2 in flight)
            else if (kg <= 21) VMCNT(4);    // drain s_{kg+1}, keep s_{kg+2}
            else if (kg == 22) VMCNT(0);    // drain s23
            if (kg < 23) BARRIER();
            // kg==23: no barrier — epilogue writes A2 (=b0/b1) whose last
            // readers (regions 21/22) are fenced by the kg==22 barrier.
        }

        // ---- epilogue: quad -> K; NT store fp32 K; bf16 K into swizzled A2 ----
        float qXv[4];
        #pragma unroll
        for (int ni = 0; ni < 4; ++ni)
            qXv[ni] = qX[jb + wc*64 + ni*16 + lc];

        #pragma unroll
        for (int mi = 0; mi < 4; ++mi) {
            const int row = ib + wr*64 + mi*16 + lq*4;
            #pragma unroll
            for (int ni = 0; ni < 4; ++ni) {
                const int col = jb + wc*64 + ni*16 + lc;
                float kq[4];
                #pragma unroll
                for (int r = 0; r < 4; ++r) {
                    float quad = qYr[mi*4 + r] + qXv[ni] - acc[mi][ni][r];
                    kq[r] = __expf(-0.5f * quad);
                    rs[mi*4 + r] += kq[r];
                }
                #pragma unroll
                for (int r = 0; r < 4; ++r)
                    __builtin_nontemporal_store(
                        kq[r], Kout + (size_t)(row + r) * NN + col);
                #pragma unroll
                for (int r = 0; r < 4; ++r) {
                    const int rl = wr*64 + mi*16 + lq*4 + r;
                    const int cl = wc*64 + ni*16 + lc;
                    const int by = rl*256 + ((cl*2) ^ ((rl & 7) << 4));
                    *reinterpret_cast<u16*>(smem + by) = f2bf(kq[r]);
                }
            }
        }
        __syncthreads();   // A2 visible to all; also drains stores/loads (vmcnt=0)

        // ---- phase 2: dacc[i][d] += K_tile[i][j] * XS[j][d] (j = K-dim) ----
        #pragma unroll
        for (int kb = 0; kb < 4; ++kb) {
            bf16x8 pa[4], pb[4];
            #pragma unroll
            for (int mi = 0; mi < 4; ++mi) {
                const int rl = wr*64 + mi*16 + lc;
                const int gr = (kb*4 + lq) ^ (rl & 7);
                pa[mi] = *reinterpret_cast<const bf16x8*>(smem + rl*256 + gr*16);
            }
            #pragma unroll
            for (int di = 0; di < 4; ++di) {
                const int dl = wc*64 + di*16 + lc;
                const int gr = (kb*4 + lq) ^ (dl & 7);
                pb[di] = *reinterpret_cast<const bf16x8*>(smem + 49152 + dl*256 + gr*16);
            }
            #pragma unroll
            for (int mi = 0; mi < 4; ++mi)
                #pragma unroll
                for (int di = 0; di < 4; ++di)
                    dacc[mi][di] = __builtin_amdgcn_mfma_f32_16x16x32_bf16(
                        pa[mi], pb[di], dacc[mi][di], 0, 0, 0);
        }
        __syncthreads();   // phase-2 reads done before next jt restages b0/b1/XT2
    }

    // write out dacc (atomic: JSPLIT blocks per i-strip) and rowsum
    #pragma unroll
    for (int mi = 0; mi < 4; ++mi) {
        const int row = ib + wr*64 + mi*16 + lq*4;
        #pragma unroll
        for (int di = 0; di < 4; ++di) {
            const int col = wc*64 + di*16 + lc;
            #pragma unroll
            for (int r = 0; r < 4; ++r)
                atomicAdd(&dKacc[(size_t)(row + r) * DD + col], dacc[mi][di][r]);
        }
    }
    #pragma unroll
    for (int q = 0; q < 16; ++q) {
        float v = rs[q];
        v += __shfl_xor(v, 1);
        v += __shfl_xor(v, 2);
        v += __shfl_xor(v, 4);
        v += __shfl_xor(v, 8);
        if (lc == 0) {
            const int mi = q >> 2, r = q & 3;
            atomicAdd(&rowsum[ib + wr*64 + mi*16 + lq*4 + r], v);
        }
    }
}

// dK = 2*(rowsum[i]*YS[i][d] - acc[i][d]); acc lives in dK buffer (in-place)
__global__ __launch_bounds__(256) void k3_finalize(
    const float* __restrict__ rowsum, const float* __restrict__ YSrm,
    float* __restrict__ dK)
{
    int idx = blockIdx.x * 256 + threadIdx.x;
    int i = idx >> 7;
    dK[idx] = 2.0f * (rowsum[i] * YSrm[idx] - dK[idx]);
}

extern "C" void kernel_launch(void* const* d_in, const int* in_sizes, int n_in,
                              void* d_out, int out_size, void* d_ws, size_t ws_size,
                              hipStream_t stream)
{
    const float* X = (const float*)d_in[0];
    const float* Y = (const float*)d_in[1];
    const float* S = (const float*)d_in[2];
    float* Kout = (float*)d_out;
    float* dK   = Kout + (size_t)NN * NN;

    u16* Ah  = (u16*)d_ws;
    u16* Al  = Ah + (size_t)NN * KP;
    u16* Bh  = Al + (size_t)NN * KP;
    u16* Bl  = Bh + (size_t)NN * KP;
    u16* XST = Bl + (size_t)NN * KP;
    float* YSrm = (float*)(XST + (size_t)DD * NN);
    float* qX   = YSrm + (size_t)NN * DD;
    float* qY   = qX + NN;
    float* rsum = qY + NN;

    hipMemsetAsync(dK, 0, (size_t)NN * DD * sizeof(float), stream);
    hipMemsetAsync(rsum, 0, (size_t)NN * sizeof(float), stream);

    k1_precompute<<<NN / 16, 256, 0, stream>>>(X, Y, S, Ah, Al, Bh, Bl, XST, YSrm, qX, qY);
    k2_main<<<64 * JSPLIT, 256, 0, stream>>>(Ah, Al, Bh, Bl, XST, qX, qY, Kout, dK, rsum);
    k3_finalize<<<(NN * DD) / 256, 256, 0, stream>>>(rsum, YSrm, dK);
}

// Round 3
// 278.918 us; speedup vs baseline: 6.5572x; 1.1172x over previous
//
#include <hip/hip_runtime.h>
#include <cstddef>
#include <cstdint>

#define NN 8192
#define DD 128
#define KP 256          // concat K per split part: [YS|Y] / [X|XS]
#define BM 128
#define BN 128
#define BK 32
#define JSPLIT 8
#define JRANGE (NN / JSPLIT)    // 1024
#define NJT (JRANGE / BN)       // 8

typedef __attribute__((ext_vector_type(8))) short bf16x8;
typedef __attribute__((ext_vector_type(4))) float f32x4;
typedef unsigned short u16;
typedef unsigned int   u32;

__device__ __forceinline__ u16 f2bf(float x) {
    u32 u = __float_as_uint(x);
    u32 r = (u + 0x7fffu + ((u >> 16) & 1u)) >> 16;   // round-to-nearest-even
    return (u16)r;
}
__device__ __forceinline__ float bf2f(u16 h) {
    return __uint_as_float(((u32)h) << 16);
}

// async global->LDS, 16B per lane; LDS dest is wave-uniform base (+lane*16 by HW)
#define GLDS16(gp, lp) __builtin_amdgcn_global_load_lds( \
    (const __attribute__((address_space(1))) void*)(gp), \
    (__attribute__((address_space(3))) void*)(lp), 16, 0, 0)

#define VMCNT(n) asm volatile("s_waitcnt vmcnt(" #n ")" ::: "memory")
#define BARRIER() do { __builtin_amdgcn_s_barrier(); asm volatile("" ::: "memory"); } while (0)

// 16B-chunk swizzle within a 64B staging row: free 2-way bank pattern on read
#define SWZ_CHUNK(row, c) ((c) ^ (((row) >> 1) & 3))

// ---------------------------------------------------------------------------
// k1: XS=X@S, YS=Y@S, qX, qY; emit bf16 hi/lo panels Ah/Al=[YS|Y], Bh/Bl=[X|XS]
// (row-major [8192][256]), XST = bf16 XS^T [128][8192], YSrm fp32 [8192][128].
// ---------------------------------------------------------------------------
__global__ __launch_bounds__(256) void k1_precompute(
    const float* __restrict__ X, const float* __restrict__ Y,
    const float* __restrict__ S,
    u16* __restrict__ Ah, u16* __restrict__ Al,
    u16* __restrict__ Bh, u16* __restrict__ Bl,
    u16* __restrict__ XST, float* __restrict__ YSrm,
    float* __restrict__ qX, float* __restrict__ qY)
{
    __shared__ float Xs[16][128];
    __shared__ float Ys[16][128];
    __shared__ float XSb[16][129];
    __shared__ float YSb[16][129];
    const int t  = threadIdx.x;
    const int i0 = blockIdx.x * 16;

    #pragma unroll
    for (int p = 0; p < 2; ++p) {
        int f4 = t + p * 256;          // 0..511
        int r  = f4 >> 5;
        int c  = (f4 & 31) * 4;
        *reinterpret_cast<float4*>(&Xs[r][c]) =
            *reinterpret_cast<const float4*>(X + (size_t)(i0 + r) * DD + c);
        *reinterpret_cast<float4*>(&Ys[r][c]) =
            *reinterpret_cast<const float4*>(Y + (size_t)(i0 + r) * DD + c);
    }
    __syncthreads();

    const int d    = t & 127;
    const int half = t >> 7;
    float xsa[8], ysa[8];
    #pragma unroll
    for (int r = 0; r < 8; ++r) { xsa[r] = 0.f; ysa[r] = 0.f; }
    for (int k = 0; k < DD; ++k) {
        float sv = S[k * DD + d];
        #pragma unroll
        for (int r = 0; r < 8; ++r) {
            xsa[r] = fmaf(Xs[half*8 + r][k], sv, xsa[r]);
            ysa[r] = fmaf(Ys[half*8 + r][k], sv, ysa[r]);
        }
    }
    #pragma unroll
    for (int r = 0; r < 8; ++r) {
        XSb[half*8 + r][d] = xsa[r];
        YSb[half*8 + r][d] = ysa[r];
    }
    __syncthreads();

    if (t < 16) {
        float s = 0.f;
        for (int k = 0; k < DD; ++k) s += Xs[t][k] * XSb[t][k];
        qX[i0 + t] = s;
    } else if (t < 32) {
        int r = t - 16;
        float s = 0.f;
        for (int k = 0; k < DD; ++k) s += Ys[r][k] * YSb[r][k];
        qY[i0 + r] = s;
    }

    // hi/lo split panels, 2 cols per u32 store
    #pragma unroll
    for (int p = 0; p < 8; ++p) {
        int e  = t + p * 256;          // 0..2047
        int r  = e >> 7;               // 0..15
        int c2 = (e & 127) * 2;        // 0,2,..,254
        float a0 = (c2     < 128) ? YSb[r][c2]         : Ys[r][c2 - 128];
        float a1 = (c2 + 1 < 128) ? YSb[r][c2 + 1]     : Ys[r][c2 + 1 - 128];
        float b0 = (c2     < 128) ? Xs[r][c2]          : XSb[r][c2 - 128];
        float b1 = (c2 + 1 < 128) ? Xs[r][c2 + 1]      : XSb[r][c2 + 1 - 128];
        u16 ah0 = f2bf(a0), ah1 = f2bf(a1);
        u16 al0 = f2bf(a0 - bf2f(ah0)), al1 = f2bf(a1 - bf2f(ah1));
        u16 bh0 = f2bf(b0), bh1 = f2bf(b1);
        u16 bl0 = f2bf(b0 - bf2f(bh0)), bl1 = f2bf(b1 - bf2f(bh1));
        size_t off = (size_t)(i0 + r) * KP + c2;
        *reinterpret_cast<u32*>(Ah + off) = (u32)ah0 | ((u32)ah1 << 16);
        *reinterpret_cast<u32*>(Al + off) = (u32)al0 | ((u32)al1 << 16);
        *reinterpret_cast<u32*>(Bh + off) = (u32)bh0 | ((u32)bh1 << 16);
        *reinterpret_cast<u32*>(Bl + off) = (u32)bl0 | ((u32)bl1 << 16);
    }
    // XS^T bf16
    #pragma unroll
    for (int p = 0; p < 8; ++p) {
        int e  = t + p * 256;          // 0..2047
        int dd = e >> 4;               // 0..127
        int r  = e & 15;
        XST[(size_t)dd * NN + i0 + r] = f2bf(XSb[r][dd]);
    }
    // YS fp32 row-major
    #pragma unroll
    for (int p = 0; p < 8; ++p) {
        int e  = t + p * 256;
        int r  = e >> 7;
        int dd = e & 127;
        YSrm[(size_t)(i0 + r) * DD + dd] = YSb[r][dd];
    }
}

// ---------------------------------------------------------------------------
// k2 (512 threads, 8 waves, 2 blocks/CU = 16 waves/CU):
// cross^T-oriented MFMA: A-operand = X-panel (j on acc regs), B = Y-panel
// (i on lane&15) -> float4 Kout stores, uint2 A2 LDS writes.
// Triple-buffered global_load_lds staging, counted vmcnt, raw barriers.
// LDS map: b0 [0,16K) b1 [16K,32K) b2 [32K,48K) XT2 [48K,80K); A2 = b0+b1.
// ---------------------------------------------------------------------------
__device__ __forceinline__ void get_ops(
    const u16* Ah, const u16* Al, const u16* Bh, const u16* Bl,
    int kg, const u16** Ap, const u16** Bp, int* kc)
{
    const int pass = kg >> 3;
    *kc = (kg & 7) * BK;
    *Ap = (pass == 2) ? Al : Ah;
    *Bp = (pass == 1) ? Bl : Bh;
}

__device__ __forceinline__ void stage_ab8(
    const u16* __restrict__ Ap, const u16* __restrict__ Bp,
    int ib, int jb, int kc, unsigned char* lds, int wid, int lane)
{
    const int rr = wid * 16 + (lane >> 2);         // row 0..127 (wave-chunk wid)
    const int cc = SWZ_CHUNK(rr, lane & 3) * 8;    // swizzled u16 col
    GLDS16(Ap + (size_t)(ib + rr) * KP + kc + cc, lds + wid * 1024);
    GLDS16(Bp + (size_t)(jb + rr) * KP + kc + cc, lds + 8192 + wid * 1024);
}

__global__ __launch_bounds__(512, 4) void k2_main(
    const u16* __restrict__ Ah, const u16* __restrict__ Al,
    const u16* __restrict__ Bh, const u16* __restrict__ Bl,
    const u16* __restrict__ XST,
    const float* __restrict__ qX, const float* __restrict__ qY,
    float* __restrict__ Kout, float* __restrict__ dKacc,
    float* __restrict__ rowsum)
{
    __shared__ unsigned char smem[81920];

    const int t    = threadIdx.x;
    const int wid  = t >> 6;                // 0..7
    const int lane = t & 63;
    const int lq   = lane >> 4;             // quarter 0..3
    const int lc   = lane & 15;
    const int wir  = wid >> 1;              // i 32-quarter (0..3)
    const int wjc  = wid & 1;               // j 64-half (0..1)

    // XCD-aware bijective swizzle (512 blocks, 8 XCDs): XCD x owns jsp x
    const int bid     = blockIdx.x;
    const int logical = ((bid & 7) << 6) | (bid >> 3);
    const int strip   = logical & 63;
    const int jsp     = logical >> 6;
    const int ib      = strip * BM;
    const int jbase   = jsp * JRANGE;

    // per-lane row constants: i = ib + wir*32 + ni*16 + lc
    float qYv[2];
    #pragma unroll
    for (int ni = 0; ni < 2; ++ni)
        qYv[ni] = qY[ib + wir*32 + ni*16 + lc];

    f32x4 dacc[2][4];
    #pragma unroll
    for (int a = 0; a < 2; ++a)
        #pragma unroll
        for (int b = 0; b < 4; ++b)
            dacc[a][b] = (f32x4){0.f, 0.f, 0.f, 0.f};
    float rs[2] = {0.f, 0.f};

    for (int jt = 0; jt < NJT; ++jt) {
        const int jb = jbase + jt * BN;

        // ---- prologue: stage kg=0 -> b0, kg=1 -> b1, then XT2 prefetch ----
        {
            const u16 *Ap, *Bp; int kc;
            get_ops(Ah, Al, Bh, Bl, 0, &Ap, &Bp, &kc);
            stage_ab8(Ap, Bp, ib, jb, kc, smem, wid, lane);
            get_ops(Ah, Al, Bh, Bl, 1, &Ap, &Bp, &kc);
            stage_ab8(Ap, Bp, ib, jb, kc, smem + 16384, wid, lane);
        }
        #pragma unroll
        for (int c = 0; c < 4; ++c) {
            int chunk = wid * 4 + c;              // 0..31
            int dd = chunk * 4 + lq;              // 0..127
            int ch = lc ^ (dd & 7);               // pre-swizzled 16B granule
            GLDS16(XST + (size_t)dd * NN + jb + ch*8,
                   smem + 49152 + (size_t)chunk * 1024);
        }
        VMCNT(6);           // s0 complete (s1 + XT2 still in flight)
        BARRIER();

        f32x4 acc[4][2];    // [mj][ni]
        #pragma unroll
        for (int a = 0; a < 4; ++a)
            #pragma unroll
            for (int b = 0; b < 2; ++b)
                acc[a][b] = (f32x4){0.f, 0.f, 0.f, 0.f};

        // ---- main pipeline: 24 regions, one barrier each, counted vmcnt ----
        #pragma unroll 3
        for (int kg = 0; kg < 24; ++kg) {
            if (kg <= 21) {
                const u16 *Ap, *Bp; int kc;
                get_ops(Ah, Al, Bh, Bl, kg + 2, &Ap, &Bp, &kc);
                stage_ab8(Ap, Bp, ib, jb, kc, smem + ((kg + 2) % 3) * 16384, wid, lane);
            }
            const u16* BufA = (const u16*)(smem + (kg % 3) * 16384);  // Y-rows
            const u16* BufB = BufA + 4096;                             // X-rows

            bf16x8 xf[4], yf[2];
            #pragma unroll
            for (int mj = 0; mj < 4; ++mj) {
                const int br = wjc*64 + mj*16 + lc;
                xf[mj] = *reinterpret_cast<const bf16x8*>(
                    BufB + br * BK + SWZ_CHUNK(br, lq) * 8);
            }
            #pragma unroll
            for (int ni = 0; ni < 2; ++ni) {
                const int ar = wir*32 + ni*16 + lc;
                yf[ni] = *reinterpret_cast<const bf16x8*>(
                    BufA + ar * BK + SWZ_CHUNK(ar, lq) * 8);
            }
            __builtin_amdgcn_s_setprio(1);
            #pragma unroll
            for (int mj = 0; mj < 4; ++mj)
                #pragma unroll
                for (int ni = 0; ni < 2; ++ni)
                    acc[mj][ni] = __builtin_amdgcn_mfma_f32_16x16x32_bf16(
                        xf[mj], yf[ni], acc[mj][ni], 0, 0, 0);
            __builtin_amdgcn_s_setprio(0);

            if (kg == 0)       VMCNT(6);    // drain s1 (XT2+s2 in flight)
            else if (kg <= 21) VMCNT(2);    // drain s_{kg+1}, keep s_{kg+2}
            else if (kg == 22) VMCNT(0);    // drain s23
            if (kg < 23) BARRIER();
            // kg==23: no barrier — epilogue writes A2 (=b0/b1) whose last
            // readers (regions 21/22) are fenced by the kg==22 barrier.
        }

        // ---- epilogue: quad -> K; float4 Kout; uint2 bf16 A2 (swizzled) ----
        #pragma unroll
        for (int mj = 0; mj < 4; ++mj) {
            const int jl = wjc*64 + mj*16 + lq*4;      // local j of reg 0
            const float4 qXv = *reinterpret_cast<const float4*>(qX + jb + jl);
            #pragma unroll
            for (int ni = 0; ni < 2; ++ni) {
                const int il = wir*32 + ni*16 + lc;    // local i
                float kq[4];
                kq[0] = __expf(-0.5f * (qYv[ni] + qXv.x - acc[mj][ni][0]));
                kq[1] = __expf(-0.5f * (qYv[ni] + qXv.y - acc[mj][ni][1]));
                kq[2] = __expf(-0.5f * (qYv[ni] + qXv.z - acc[mj][ni][2]));
                kq[3] = __expf(-0.5f * (qYv[ni] + qXv.w - acc[mj][ni][3]));
                rs[ni] += kq[0] + kq[1] + kq[2] + kq[3];
                *reinterpret_cast<float4*>(Kout + (size_t)(ib + il) * NN + jb + jl) =
                    make_float4(kq[0], kq[1], kq[2], kq[3]);
                // bf16 into A2 [i][j] row-major, 16B-granule XOR swizzle
                u32 p0 = (u32)f2bf(kq[0]) | ((u32)f2bf(kq[1]) << 16);
                u32 p1 = (u32)f2bf(kq[2]) | ((u32)f2bf(kq[3]) << 16);
                const int by = il*256 + ((jl*2) ^ ((il & 7) << 4));
                *reinterpret_cast<uint2*>(smem + by) = make_uint2(p0, p1);
            }
        }
        __syncthreads();   // A2 visible to all; XT2 loads long since drained

        // ---- phase 2: dacc[i][d] += K_tile[i][j] * XS[j][d] (j = K-dim) ----
        #pragma unroll
        for (int kb = 0; kb < 4; ++kb) {
            bf16x8 pa[2], pb[4];
            #pragma unroll
            for (int mi = 0; mi < 2; ++mi) {
                const int il = wir*32 + mi*16 + lc;
                const int gr = (kb*4 + lq) ^ (il & 7);
                pa[mi] = *reinterpret_cast<const bf16x8*>(smem + il*256 + gr*16);
            }
            #pragma unroll
            for (int di = 0; di < 4; ++di) {
                const int dl = wjc*64 + di*16 + lc;
                const int gr = (kb*4 + lq) ^ (dl & 7);
                pb[di] = *reinterpret_cast<const bf16x8*>(smem + 49152 + dl*256 + gr*16);
            }
            #pragma unroll
            for (int mi = 0; mi < 2; ++mi)
                #pragma unroll
                for (int di = 0; di < 4; ++di)
                    dacc[mi][di] = __builtin_amdgcn_mfma_f32_16x16x32_bf16(
                        pa[mi], pb[di], dacc[mi][di], 0, 0, 0);
        }
        __syncthreads();   // phase-2 reads done before next jt restages
    }

    // write out dacc (atomic: JSPLIT blocks per i-strip) and rowsum
    #pragma unroll
    for (int mi = 0; mi < 2; ++mi) {
        #pragma unroll
        for (int di = 0; di < 4; ++di) {
            const int col = wjc*64 + di*16 + lc;
            #pragma unroll
            for (int r = 0; r < 4; ++r) {
                const int row = ib + wir*32 + mi*16 + lq*4 + r;
                atomicAdd(&dKacc[(size_t)row * DD + col], dacc[mi][di][r]);
            }
        }
    }
    #pragma unroll
    for (int ni = 0; ni < 2; ++ni) {
        float v = rs[ni];
        v += __shfl_xor(v, 16);
        v += __shfl_xor(v, 32);
        if (lq == 0)
            atomicAdd(&rowsum[ib + wir*32 + ni*16 + lc], v);
    }
}

// dK = 2*(rowsum[i]*YS[i][d] - acc[i][d]); acc lives in dK buffer (in-place)
__global__ __launch_bounds__(256) void k3_finalize(
    const float* __restrict__ rowsum, const float* __restrict__ YSrm,
    float* __restrict__ dK)
{
    int idx = blockIdx.x * 256 + threadIdx.x;
    int i = idx >> 7;
    dK[idx] = 2.0f * (rowsum[i] * YSrm[idx] - dK[idx]);
}

extern "C" void kernel_launch(void* const* d_in, const int* in_sizes, int n_in,
                              void* d_out, int out_size, void* d_ws, size_t ws_size,
                              hipStream_t stream)
{
    const float* X = (const float*)d_in[0];
    const float* Y = (const float*)d_in[1];
    const float* S = (const float*)d_in[2];
    float* Kout = (float*)d_out;
    float* dK   = Kout + (size_t)NN * NN;

    u16* Ah  = (u16*)d_ws;
    u16* Al  = Ah + (size_t)NN * KP;
    u16* Bh  = Al + (size_t)NN * KP;
    u16* Bl  = Bh + (size_t)NN * KP;
    u16* XST = Bl + (size_t)NN * KP;
    float* YSrm = (float*)(XST + (size_t)DD * NN);
    float* qX   = YSrm + (size_t)NN * DD;
    float* qY   = qX + NN;
    float* rsum = qY + NN;

    hipMemsetAsync(dK, 0, (size_t)NN * DD * sizeof(float), stream);
    hipMemsetAsync(rsum, 0, (size_t)NN * sizeof(float), stream);

    k1_precompute<<<NN / 16, 256, 0, stream>>>(X, Y, S, Ah, Al, Bh, Bl, XST, YSrm, qX, qY);
    k2_main<<<64 * JSPLIT, 512, 0, stream>>>(Ah, Al, Bh, Bl, XST, qX, qY, Kout, dK, rsum);
    k3_finalize<<<(NN * DD) / 256, 256, 0, stream>>>(rsum, YSrm, dK);
}